// Round 9
// baseline (708.444 us; speedup 1.0000x reference)
//
#include <hip/hip_runtime.h>
#include <math.h>

#define NN 25000
#define NE 400000
#define CH 256          // T*64 channels
#define NPB 8           // nodes per block in agg/mlp
#define SP 9            // padded node-dim of S (breaks single-bank column)

// ---------------- FMA helper: acc[0..7] += w * ptr[0..7] (LDS, b128 pairs) --
#define FMA8(dst, w, ptr) do {                                   \
    const float4 _u0 = *(const float4*)(ptr);                    \
    const float4 _u1 = *(const float4*)((ptr)+4);                \
    dst[0]=fmaf((w),_u0.x,dst[0]); dst[1]=fmaf((w),_u0.y,dst[1]);\
    dst[2]=fmaf((w),_u0.z,dst[2]); dst[3]=fmaf((w),_u0.w,dst[3]);\
    dst[4]=fmaf((w),_u1.x,dst[4]); dst[5]=fmaf((w),_u1.y,dst[5]);\
    dst[6]=fmaf((w),_u1.z,dst[6]); dst[7]=fmaf((w),_u1.w,dst[7]);} while(0)

// component-wise accumulate of one gathered float4
#define ACC4(sv, qv, mnv, mxv, v) do {                                  \
    sv.x += v.x; qv.x = fmaf(v.x, v.x, qv.x);                           \
    mnv.x = fminf(mnv.x, v.x); mxv.x = fmaxf(mxv.x, v.x);               \
    sv.y += v.y; qv.y = fmaf(v.y, v.y, qv.y);                           \
    mnv.y = fminf(mnv.y, v.y); mxv.y = fmaxf(mxv.y, v.y);               \
    sv.z += v.z; qv.z = fmaf(v.z, v.z, qv.z);                           \
    mnv.z = fminf(mnv.z, v.z); mxv.z = fmaxf(mxv.z, v.z);               \
    sv.w += v.w; qv.w = fmaf(v.w, v.w, qv.w);                           \
    mnv.w = fminf(mnv.w, v.w); mxv.w = fmaxf(mxv.w, v.w); } while(0)

// BN-apply + ReLU on a loaded value (stats via bn_sum/bn_sum2 atomics)
__device__ __forceinline__ float bn_relu(float x, int c, const float* bs,
                                         const float* bs2, const float* g,
                                         const float* b) {
    const float invN = 1.f / (float)NN;
    float m = bs[c] * invN;
    float v = bs2[c] * invN - m * m;
    float sc = g[c] / sqrtf(v + 1e-5f);
    return fmaxf(sc * (x - m) + b[c], 0.f);
}

// ---------------- degree histogram -----------------------------------------
__global__ void k_hist(const int* __restrict__ dst, int* __restrict__ cnt) {
    int e = blockIdx.x * 256 + threadIdx.x;
    if (e < NE) atomicAdd(&cnt[dst[e]], 1);
}

// ---------------- single-block scan (1024 thr, 2-pass, ~3 barriers) --------
__global__ __launch_bounds__(1024) void k_scan(const int* __restrict__ cnt,
                                               int* __restrict__ offs,
                                               float* __restrict__ avg_log) {
    __shared__ int wsum[16];
    __shared__ float wlog[16];
    const int tid = threadIdx.x;
    const int lane = tid & 63, wv = tid >> 6;
    const int PER = (NN + 1023) / 1024;   // 25 contiguous elements per thread
    const int start = tid * PER;
    int lsum = 0;
    float llog = 0.f;
    for (int j = 0; j < PER; ++j) {
        int i = start + j;
        if (i < NN) {
            int c = cnt[i];
            lsum += c;
            llog += logf((float)c + 1.f);
        }
    }
    // wave-inclusive scan of per-thread sums
    int v = lsum;
    for (int d = 1; d < 64; d <<= 1) {
        int t = __shfl_up(v, d);
        if (lane >= d) v += t;
    }
    if (lane == 63) wsum[wv] = v;
    float lg = llog;
    for (int d = 32; d > 0; d >>= 1) lg += __shfl_xor(lg, d);
    if (lane == 0) wlog[wv] = lg;
    __syncthreads();
    if (tid == 0) {
        int run = 0;
        for (int w = 0; w < 16; ++w) { int t = wsum[w]; wsum[w] = run; run += t; }
        offs[NN] = run;
        float lt = 0.f;
        for (int w = 0; w < 16; ++w) lt += wlog[w];
        *avg_log = lt / (float)NN;
    }
    __syncthreads();
    int base = wsum[wv] + (v - lsum);   // exclusive prefix for this thread
    for (int j = 0; j < PER; ++j) {
        int i = start + j;
        if (i < NN) {
            offs[i] = base;
            base += cnt[i];
        }
    }
}

// ---------------- CSR scatter ----------------------------------------------
__global__ void k_scatter(const int* __restrict__ src, const int* __restrict__ dst,
                          const int* __restrict__ offs, int* __restrict__ cursor,
                          int* __restrict__ adj) {
    int e = blockIdx.x * 256 + threadIdx.x;
    if (e < NE) {
        int d = dst[e];
        int p = atomicAdd(&cursor[d], 1);
        adj[offs[d] + p] = src[e];
    }
}

// ---------------- transpose pre weights: wit/wjt [f][c], c=t*64+g ----------
__global__ void k_wt(const float* __restrict__ pre_w, float* __restrict__ wit,
                     float* __restrict__ wjt) {
    int i = blockIdx.x * 256 + threadIdx.x;   // over 64*256
    int f = i >> 8, c = i & 255;
    int t = c >> 6, g = c & 63;
    wit[f * CH + c] = pre_w[(t * 64 + g) * 128 + f];
    wjt[f * CH + c] = pre_w[(t * 64 + g) * 128 + 64 + f];
}

// ---------------- pre GEMM: A = X@Wi^T + pre_b, NJ = X@Wj^T ----------------
// apply_bn: input is pre-BN (Hpre); apply bn_relu inline while staging.
__global__ __launch_bounds__(256) void k_pre(
        const float* __restrict__ X, const float* __restrict__ wit,
        const float* __restrict__ wjt, const float* __restrict__ pre_b,
        float* __restrict__ A, float* __restrict__ NJv,
        int apply_bn, const float* __restrict__ bs, const float* __restrict__ bs2,
        const float* __restrict__ bng, const float* __restrict__ bnb) {
    __shared__ __align__(16) float xl[16][64];
    const int tid = threadIdx.x;
    const int base = blockIdx.x * 16;
#pragma unroll
    for (int r = 0; r < 4; ++r) {
        int idx = r * 256 + tid;
        int nn = idx >> 6, f = idx & 63;
        int n = base + nn;
        float xv = (n < NN) ? X[n * 64 + f] : 0.f;
        if (apply_bn) xv = bn_relu(xv, f, bs, bs2, bng, bnb);
        xl[nn][f] = xv;
    }
    __syncthreads();
    const int c = tid;
    float accA[16], accJ[16];
#pragma unroll
    for (int j = 0; j < 16; ++j) { accA[j] = 0.f; accJ[j] = 0.f; }
#pragma unroll 4
    for (int f = 0; f < 64; ++f) {
        float wa = wit[f * CH + c];
        float wb = wjt[f * CH + c];
#pragma unroll
        for (int nn = 0; nn < 16; ++nn) {
            float xv = xl[nn][f];
            accA[nn] = fmaf(wa, xv, accA[nn]);
            accJ[nn] = fmaf(wb, xv, accJ[nn]);
        }
    }
    float pb = pre_b[c];
#pragma unroll
    for (int nn = 0; nn < 16; ++nn) {
        int n = base + nn;
        if (n < NN) {
            A[n * CH + c]   = accA[nn] + pb;
            NJv[n * CH + c] = accJ[nn];
        }
    }
}

// ---------------- fused aggregate + post matmul + lin + BN stats -----------
// grid = NN/NPB = 3125 blocks of 256 threads (exact, no tail)
// Phase 1: wave w owns nodes {w, w+4}; lane gathers float4 (4 channels);
// 8/4/1 unroll ladder => up to 8 independent 16B gathers in flight.
// apply_bn: X is pre-BN Hpre from previous layer (row-disjoint R/W safe).
__global__ __attribute__((amdgpu_waves_per_eu(4, 4))) __launch_bounds__(256)
void k_agg(
        const float* __restrict__ X, const float* __restrict__ A,
        const float* __restrict__ NJv, const int* __restrict__ offs,
        const int* __restrict__ adj, const float* __restrict__ avg_log_p,
        const float* __restrict__ post_w, const float* __restrict__ post_b,
        const float* __restrict__ lin_w, const float* __restrict__ lin_b,
        float* __restrict__ Hpre, float* __restrict__ bn_sum,
        float* __restrict__ bn_sum2,
        int apply_bn, const float* __restrict__ pbs, const float* __restrict__ pbs2,
        const float* __restrict__ pg, const float* __restrict__ pb2) {
    __shared__ __align__(16) float S[4][CH][SP];    // mean,min,max,std  [stat][ch][node(+pad)]
    __shared__ __align__(16) float xl[64][NPB];     // [f][node]; reused as Zl in phase 3
    __shared__ float ampl[NPB], ivampl[NPB];
    float (*Zl)[NPB] = xl;                          // alias: xl dead after region 0
    const int tid = threadIdx.x;
    const int base = blockIdx.x * NPB;
    const float avg_log = *avg_log_p;

#pragma unroll
    for (int r = 0; r < 2; ++r) {
        int idx = r * 256 + tid;
        int nn = idx >> 6, f = idx & 63;
        float xv = X[(base + nn) * 64 + f];
        if (apply_bn) xv = bn_relu(xv, f, pbs, pbs2, pg, pb2);
        xl[f][nn] = xv;
    }

    // ---- phase 1: per-node segment stats, float4-per-lane gather ----
    const int wid = tid >> 6, lane = tid & 63;
    const int c4 = lane << 2;                         // channel base (0,4,..252)
    const float4* __restrict__ njv4 = (const float4*)NJv;   // [n*64 + lane]
#pragma unroll
    for (int pass = 0; pass < 2; ++pass) {
        const int nn = wid + pass * 4;
        const int n = base + nn;
        const float4 a4 = *(const float4*)&A[n * CH + c4];
        const int e0 = offs[n], e1 = offs[n + 1];
        float4 s0, s1, q0, q1, mn, mx;
        s0.x=s0.y=s0.z=s0.w=0.f; s1=s0; q0=s0; q1=s0;
        mn.x=mn.y=mn.z=mn.w= __builtin_inff();
        mx.x=mx.y=mx.z=mx.w=-__builtin_inff();
        int e = e0;
        for (; e + 8 <= e1; e += 8) {                 // 8 gathers in flight
            int i0 = adj[e + 0];
            int i1 = adj[e + 1];
            int i2 = adj[e + 2];
            int i3 = adj[e + 3];
            int i4 = adj[e + 4];
            int i5 = adj[e + 5];
            int i6 = adj[e + 6];
            int i7 = adj[e + 7];
            float4 v0 = njv4[(size_t)i0 * 64 + lane];
            float4 v1 = njv4[(size_t)i1 * 64 + lane];
            float4 v2 = njv4[(size_t)i2 * 64 + lane];
            float4 v3 = njv4[(size_t)i3 * 64 + lane];
            float4 v4 = njv4[(size_t)i4 * 64 + lane];
            float4 v5 = njv4[(size_t)i5 * 64 + lane];
            float4 v6 = njv4[(size_t)i6 * 64 + lane];
            float4 v7 = njv4[(size_t)i7 * 64 + lane];
            ACC4(s0, q0, mn, mx, v0);
            ACC4(s1, q1, mn, mx, v1);
            ACC4(s0, q0, mn, mx, v2);
            ACC4(s1, q1, mn, mx, v3);
            ACC4(s0, q0, mn, mx, v4);
            ACC4(s1, q1, mn, mx, v5);
            ACC4(s0, q0, mn, mx, v6);
            ACC4(s1, q1, mn, mx, v7);
        }
        for (; e + 4 <= e1; e += 4) {
            int i0 = adj[e + 0];
            int i1 = adj[e + 1];
            int i2 = adj[e + 2];
            int i3 = adj[e + 3];
            float4 v0 = njv4[(size_t)i0 * 64 + lane];
            float4 v1 = njv4[(size_t)i1 * 64 + lane];
            float4 v2 = njv4[(size_t)i2 * 64 + lane];
            float4 v3 = njv4[(size_t)i3 * 64 + lane];
            ACC4(s0, q0, mn, mx, v0);
            ACC4(s1, q1, mn, mx, v1);
            ACC4(s0, q0, mn, mx, v2);
            ACC4(s1, q1, mn, mx, v3);
        }
        for (; e < e1; ++e) {
            int s = adj[e];
            float4 v = njv4[(size_t)s * 64 + lane];
            ACC4(s0, q0, mn, mx, v);
        }
        const float kf = (float)(e1 - e0);
        const float deg = fmaxf(kf, 1.f);
        const float inv_deg = 1.f / deg;
        const bool he = (e1 > e0);
        float bsum[4]  = { s0.x + s1.x, s0.y + s1.y, s0.z + s1.z, s0.w + s1.w };
        float bsum2[4] = { q0.x + q1.x, q0.y + q1.y, q0.z + q1.z, q0.w + q1.w };
        float bmin[4]  = { mn.x, mn.y, mn.z, mn.w };
        float bmax[4]  = { mx.x, mx.y, mx.z, mx.w };
        float av[4]    = { a4.x, a4.y, a4.z, a4.w };
#pragma unroll
        for (int j = 0; j < 4; ++j) {
            float a = av[j];
            float mean = (kf * a + bsum[j]) * inv_deg;
            float s2 = fmaf(kf * a, a, fmaf(2.f * a, bsum[j], bsum2[j]));
            float var = fmaxf(s2 * inv_deg - mean * mean, 0.f);
            float stdv = sqrtf(var + 1e-5f);
            int c = c4 + j;
            S[0][c][nn] = mean;
            S[1][c][nn] = he ? a + bmin[j] : 0.f;
            S[2][c][nn] = he ? a + bmax[j] : 0.f;
            S[3][c][nn] = stdv;
        }
        if (lane == 0) {
            float amp = logf(deg + 1.f) / avg_log;
            ampl[nn] = amp;
            ivampl[nn] = 1.f / amp;
        }
    }
    __syncthreads();

    // ---- phase 2: post matmul. group (o, q): o=output (t*16+go), q strides k
    const int o = tid >> 2, q = tid & 3;
    const int t = o >> 4;
    const float* pwrow = post_w + o * 832;
    float ax[8], aa[8], ab[8];
#pragma unroll
    for (int j = 0; j < 8; ++j) { ax[j] = 0.f; aa[j] = 0.f; ab[j] = 0.f; }
    // region 0: x broadcast, k in [0,64)  (xl aligned, b128 ok)
    for (int i = 0; i < 16; ++i) {
        int k = q + 4 * i;
        float w = pwrow[k];
        FMA8(ax, w, &xl[k][0]);
    }
    // regions 1-3 merged: read each S value once, 3 FMAs (w_amp, w_inv, w_id)
    for (int i = 0; i < 64; ++i) {
        int rem = q + 4 * i;
        const float* sr = &S[rem >> 6][(t << 6) | (rem & 63)][0];
        float w1 = pwrow[64 + rem];
        float w2 = pwrow[320 + rem];
        float w3 = pwrow[576 + rem];
        float sv[8];
#pragma unroll
        for (int j = 0; j < 8; ++j) sv[j] = sr[j];
#pragma unroll
        for (int j = 0; j < 8; ++j) {
            aa[j] = fmaf(w1, sv[j], aa[j]);
            ab[j] = fmaf(w2, sv[j], ab[j]);
            ax[j] = fmaf(w3, sv[j], ax[j]);
        }
    }
    float pb = post_b[o];
    float tot[8];
#pragma unroll
    for (int j = 0; j < 8; ++j) {
        float v = ax[j] + ampl[j] * aa[j] + ivampl[j] * ab[j];
        v += __shfl_xor(v, 1);
        v += __shfl_xor(v, 2);
        tot[j] = v + pb;
    }
    __syncthreads();            // all xl reads done; safe to overwrite (Zl alias)
    if (q == 0) {
#pragma unroll
        for (int j = 0; j < 8; ++j) Zl[o][j] = tot[j];
    }
    __syncthreads();

    // ---- phase 3: lin (64x64) + bias + BN stats ----
    const float* lrow = lin_w + o * 64;
    float la[8];
#pragma unroll
    for (int j = 0; j < 8; ++j) la[j] = 0.f;
    for (int i = 0; i < 16; ++i) {
        int c2 = q + 4 * i;
        float w = lrow[c2];
        FMA8(la, w, &Zl[c2][0]);
    }
#pragma unroll
    for (int j = 0; j < 8; ++j) {
        la[j] += __shfl_xor(la[j], 1);
        la[j] += __shfl_xor(la[j], 2);
    }
    if (q == 0) {
        float lb = lin_b[o];
        float s1 = 0.f, s2s = 0.f;
#pragma unroll
        for (int j = 0; j < 8; ++j) {
            float hv = la[j] + lb;
            Hpre[(base + j) * 64 + o] = hv;
            s1 += hv;
            s2s = fmaf(hv, hv, s2s);
        }
        atomicAdd(&bn_sum[o], s1);
        atomicAdd(&bn_sum2[o], s2s);
    }
}

// ---------------- fused 2-layer MLP (applies bn2 inline) -------------------
__global__ __launch_bounds__(256) void k_mlp(
        const float* __restrict__ Hpre, const float* __restrict__ w1,
        const float* __restrict__ b1, const float* __restrict__ w2,
        const float* __restrict__ b2, float* __restrict__ out,
        const float* __restrict__ bs, const float* __restrict__ bs2,
        const float* __restrict__ bng, const float* __restrict__ bnb) {
    __shared__ __align__(16) float xl[64][NPB];
    __shared__ __align__(16) float hl[64][NPB];
    const int tid = threadIdx.x;
    const int base = blockIdx.x * NPB;
#pragma unroll
    for (int r = 0; r < 2; ++r) {
        int idx = r * 256 + tid;
        int nn = idx >> 6, f = idx & 63;
        xl[f][nn] = bn_relu(Hpre[(base + nn) * 64 + f], f, bs, bs2, bng, bnb);
    }
    __syncthreads();
    const int o = tid >> 2, q = tid & 3;
    const float* wrow = w1 + o * 64;
    float acc[8];
#pragma unroll
    for (int j = 0; j < 8; ++j) acc[j] = 0.f;
    for (int i = 0; i < 16; ++i) {
        int c2 = q + 4 * i;
        float w = wrow[c2];
        FMA8(acc, w, &xl[c2][0]);
    }
#pragma unroll
    for (int j = 0; j < 8; ++j) {
        acc[j] += __shfl_xor(acc[j], 1);
        acc[j] += __shfl_xor(acc[j], 2);
    }
    if (q == 0) {
        float bb = b1[o];
#pragma unroll
        for (int j = 0; j < 8; ++j) hl[o][j] = fmaxf(acc[j] + bb, 0.f);
    }
    __syncthreads();
    // layer 2: 32 outputs, groups of 8 threads
    const int o2 = tid >> 3, q2 = tid & 7;
    const float* w2row = w2 + o2 * 64;
    float a2[8];
#pragma unroll
    for (int j = 0; j < 8; ++j) a2[j] = 0.f;
    for (int i = 0; i < 8; ++i) {
        int c2 = q2 + 8 * i;
        float w = w2row[c2];
        FMA8(a2, w, &hl[c2][0]);
    }
#pragma unroll
    for (int j = 0; j < 8; ++j) {
        a2[j] += __shfl_xor(a2[j], 1);
        a2[j] += __shfl_xor(a2[j], 2);
        a2[j] += __shfl_xor(a2[j], 4);
    }
    if (q2 == 0) {
        float bb = b2[o2];
#pragma unroll
        for (int j = 0; j < 8; ++j) out[(base + j) * 32 + o2] = a2[j] + bb;
    }
}

// ---------------------------------------------------------------------------
extern "C" void kernel_launch(void* const* d_in, const int* in_sizes, int n_in,
                              void* d_out, int out_size, void* d_ws, size_t ws_size,
                              hipStream_t stream) {
    (void)in_sizes; (void)n_in; (void)out_size; (void)ws_size;
    const float* x         = (const float*)d_in[0];
    const int*   ei        = (const int*)d_in[1];
    const float* c1_pre_w  = (const float*)d_in[2];
    const float* c1_pre_b  = (const float*)d_in[3];
    const float* c1_post_w = (const float*)d_in[4];
    const float* c1_post_b = (const float*)d_in[5];
    const float* c1_lin_w  = (const float*)d_in[6];
    const float* c1_lin_b  = (const float*)d_in[7];
    const float* c2_pre_w  = (const float*)d_in[8];
    const float* c2_pre_b  = (const float*)d_in[9];
    const float* c2_post_w = (const float*)d_in[10];
    const float* c2_post_b = (const float*)d_in[11];
    const float* c2_lin_w  = (const float*)d_in[12];
    const float* c2_lin_b  = (const float*)d_in[13];
    const float* bn1_g     = (const float*)d_in[14];
    const float* bn1_b     = (const float*)d_in[15];
    const float* bn2_g     = (const float*)d_in[16];
    const float* bn2_b     = (const float*)d_in[17];
    const float* mlp_w1    = (const float*)d_in[18];
    const float* mlp_b1    = (const float*)d_in[19];
    const float* mlp_w2    = (const float*)d_in[20];
    const float* mlp_b2    = (const float*)d_in[21];

    const int* src = ei;          // edge_index[0]
    const int* dst = ei + NE;     // edge_index[1]

    // workspace layout (all 4-byte elements)
    int*   cnt    = (int*)d_ws;                 // N        (zeroed)
    int*   cursor = cnt + NN;                   // N        (zeroed)
    float* bn1s   = (float*)(cursor + NN);      // 64       (zeroed)
    float* bn1s2  = bn1s + 64;                  // 64       (zeroed)
    float* bn2s   = bn1s2 + 64;                 // 64       (zeroed)
    float* bn2s2  = bn2s + 64;                  // 64       (zeroed)
    int*   offs   = (int*)(bn2s2 + 64);         // N+1
    float* avgl   = (float*)(offs + NN + 1);    // 1
    int*   adj    = (int*)(avgl + 1);           // E
    float* wit    = (float*)(adj + NE);         // 64*256
    float* wjt    = wit + 64 * CH;              // 64*256
    float* A      = wjt + 64 * CH;              // N*256
    float* NJv    = A + (size_t)NN * CH;        // N*256
    float* Hpre   = NJv + (size_t)NN * CH;      // N*64

    hipMemsetAsync(d_ws, 0, (size_t)(2 * NN + 256) * sizeof(int), stream);

    k_hist   <<<(NE + 255) / 256, 256, 0, stream>>>(dst, cnt);
    k_scan   <<<1, 1024, 0, stream>>>(cnt, offs, avgl);
    k_scatter<<<(NE + 255) / 256, 256, 0, stream>>>(src, dst, offs, cursor, adj);

    // layer 1
    k_wt <<<64, 256, 0, stream>>>(c1_pre_w, wit, wjt);
    k_pre<<<(NN + 15) / 16, 256, 0, stream>>>(x, wit, wjt, c1_pre_b, A, NJv,
                                              0, nullptr, nullptr, nullptr, nullptr);
    k_agg<<<NN / NPB, 256, 0, stream>>>(x, A, NJv, offs, adj, avgl,
                                        c1_post_w, c1_post_b, c1_lin_w, c1_lin_b,
                                        Hpre, bn1s, bn1s2,
                                        0, nullptr, nullptr, nullptr, nullptr);

    // layer 2 (bn1 applied inline by consumers of Hpre)
    k_wt <<<64, 256, 0, stream>>>(c2_pre_w, wit, wjt);
    k_pre<<<(NN + 15) / 16, 256, 0, stream>>>(Hpre, wit, wjt, c2_pre_b, A, NJv,
                                              1, bn1s, bn1s2, bn1_g, bn1_b);
    k_agg<<<NN / NPB, 256, 0, stream>>>(Hpre, A, NJv, offs, adj, avgl,
                                        c2_post_w, c2_post_b, c2_lin_w, c2_lin_b,
                                        Hpre, bn2s, bn2s2,
                                        1, bn1s, bn1s2, bn1_g, bn1_b);

    // MLP head (bn2 applied inline)
    k_mlp<<<NN / NPB, 256, 0, stream>>>(Hpre, mlp_w1, mlp_b1, mlp_w2, mlp_b2,
                                        (float*)d_out, bn2s, bn2s2, bn2_g, bn2_b);
}

// Round 11
// 704.546 us; speedup vs baseline: 1.0055x; 1.0055x over previous
//
#include <hip/hip_runtime.h>
#include <math.h>

#define NN 25000
#define NE 400000
#define CH 256          // T*64 channels
#define NPB 8           // nodes per block in agg/mlp
#define SP 9            // padded node-dim of S (breaks single-bank column)

// ---------------- FMA helper: acc[0..7] += w * ptr[0..7] (LDS, b128 pairs) --
#define FMA8(dst, w, ptr) do {                                   \
    const float4 _u0 = *(const float4*)(ptr);                    \
    const float4 _u1 = *(const float4*)((ptr)+4);                \
    dst[0]=fmaf((w),_u0.x,dst[0]); dst[1]=fmaf((w),_u0.y,dst[1]);\
    dst[2]=fmaf((w),_u0.z,dst[2]); dst[3]=fmaf((w),_u0.w,dst[3]);\
    dst[4]=fmaf((w),_u1.x,dst[4]); dst[5]=fmaf((w),_u1.y,dst[5]);\
    dst[6]=fmaf((w),_u1.z,dst[6]); dst[7]=fmaf((w),_u1.w,dst[7]);} while(0)

// component-wise accumulate of one gathered float4
#define ACC4(sv, qv, mnv, mxv, v) do {                                  \
    sv.x += v.x; qv.x = fmaf(v.x, v.x, qv.x);                           \
    mnv.x = fminf(mnv.x, v.x); mxv.x = fmaxf(mxv.x, v.x);               \
    sv.y += v.y; qv.y = fmaf(v.y, v.y, qv.y);                           \
    mnv.y = fminf(mnv.y, v.y); mxv.y = fmaxf(mxv.y, v.y);               \
    sv.z += v.z; qv.z = fmaf(v.z, v.z, qv.z);                           \
    mnv.z = fminf(mnv.z, v.z); mxv.z = fmaxf(mxv.z, v.z);               \
    sv.w += v.w; qv.w = fmaf(v.w, v.w, qv.w);                           \
    mnv.w = fminf(mnv.w, v.w); mxv.w = fmaxf(mxv.w, v.w); } while(0)

// BN-apply + ReLU on a loaded value (stats via bn_sum/bn_sum2 atomics)
__device__ __forceinline__ float bn_relu(float x, int c, const float* bs,
                                         const float* bs2, const float* g,
                                         const float* b) {
    const float invN = 1.f / (float)NN;
    float m = bs[c] * invN;
    float v = bs2[c] * invN - m * m;
    float sc = g[c] / sqrtf(v + 1e-5f);
    return fmaxf(sc * (x - m) + b[c], 0.f);
}

// ---------------- degree histogram -----------------------------------------
__global__ void k_hist(const int* __restrict__ dst, int* __restrict__ cnt) {
    int e = blockIdx.x * 256 + threadIdx.x;
    if (e < NE) atomicAdd(&cnt[dst[e]], 1);
}

// ---------------- single-block scan (1024 thr, 2-pass, ~3 barriers) --------
__global__ __launch_bounds__(1024) void k_scan(const int* __restrict__ cnt,
                                               int* __restrict__ offs,
                                               float* __restrict__ avg_log) {
    __shared__ int wsum[16];
    __shared__ float wlog[16];
    const int tid = threadIdx.x;
    const int lane = tid & 63, wv = tid >> 6;
    const int PER = (NN + 1023) / 1024;   // 25 contiguous elements per thread
    const int start = tid * PER;
    int lsum = 0;
    float llog = 0.f;
    for (int j = 0; j < PER; ++j) {
        int i = start + j;
        if (i < NN) {
            int c = cnt[i];
            lsum += c;
            llog += logf((float)c + 1.f);
        }
    }
    // wave-inclusive scan of per-thread sums
    int v = lsum;
    for (int d = 1; d < 64; d <<= 1) {
        int t = __shfl_up(v, d);
        if (lane >= d) v += t;
    }
    if (lane == 63) wsum[wv] = v;
    float lg = llog;
    for (int d = 32; d > 0; d >>= 1) lg += __shfl_xor(lg, d);
    if (lane == 0) wlog[wv] = lg;
    __syncthreads();
    if (tid == 0) {
        int run = 0;
        for (int w = 0; w < 16; ++w) { int t = wsum[w]; wsum[w] = run; run += t; }
        offs[NN] = run;
        float lt = 0.f;
        for (int w = 0; w < 16; ++w) lt += wlog[w];
        *avg_log = lt / (float)NN;
    }
    __syncthreads();
    int base = wsum[wv] + (v - lsum);   // exclusive prefix for this thread
    for (int j = 0; j < PER; ++j) {
        int i = start + j;
        if (i < NN) {
            offs[i] = base;
            base += cnt[i];
        }
    }
}

// ---------------- CSR scatter ----------------------------------------------
__global__ void k_scatter(const int* __restrict__ src, const int* __restrict__ dst,
                          const int* __restrict__ offs, int* __restrict__ cursor,
                          int* __restrict__ adj) {
    int e = blockIdx.x * 256 + threadIdx.x;
    if (e < NE) {
        int d = dst[e];
        int p = atomicAdd(&cursor[d], 1);
        adj[offs[d] + p] = src[e];
    }
}

// ---------------- transpose pre weights: wit/wjt [f][c], c=t*64+g ----------
__global__ void k_wt(const float* __restrict__ pre_w, float* __restrict__ wit,
                     float* __restrict__ wjt) {
    int i = blockIdx.x * 256 + threadIdx.x;   // over 64*256
    int f = i >> 8, c = i & 255;
    int t = c >> 6, g = c & 63;
    wit[f * CH + c] = pre_w[(t * 64 + g) * 128 + f];
    wjt[f * CH + c] = pre_w[(t * 64 + g) * 128 + 64 + f];
}

// ---------------- pre GEMM: A = X@Wi^T + pre_b, NJ = X@Wj^T ----------------
// apply_bn: input is pre-BN (Hpre); apply bn_relu inline while staging.
__global__ __launch_bounds__(256) void k_pre(
        const float* __restrict__ X, const float* __restrict__ wit,
        const float* __restrict__ wjt, const float* __restrict__ pre_b,
        float* __restrict__ A, float* __restrict__ NJv,
        int apply_bn, const float* __restrict__ bs, const float* __restrict__ bs2,
        const float* __restrict__ bng, const float* __restrict__ bnb) {
    __shared__ __align__(16) float xl[16][64];
    const int tid = threadIdx.x;
    const int base = blockIdx.x * 16;
#pragma unroll
    for (int r = 0; r < 4; ++r) {
        int idx = r * 256 + tid;
        int nn = idx >> 6, f = idx & 63;
        int n = base + nn;
        float xv = (n < NN) ? X[n * 64 + f] : 0.f;
        if (apply_bn) xv = bn_relu(xv, f, bs, bs2, bng, bnb);
        xl[nn][f] = xv;
    }
    __syncthreads();
    const int c = tid;
    float accA[16], accJ[16];
#pragma unroll
    for (int j = 0; j < 16; ++j) { accA[j] = 0.f; accJ[j] = 0.f; }
#pragma unroll 4
    for (int f = 0; f < 64; ++f) {
        float wa = wit[f * CH + c];
        float wb = wjt[f * CH + c];
#pragma unroll
        for (int nn = 0; nn < 16; ++nn) {
            float xv = xl[nn][f];
            accA[nn] = fmaf(wa, xv, accA[nn]);
            accJ[nn] = fmaf(wb, xv, accJ[nn]);
        }
    }
    float pb = pre_b[c];
#pragma unroll
    for (int nn = 0; nn < 16; ++nn) {
        int n = base + nn;
        if (n < NN) {
            A[n * CH + c]   = accA[nn] + pb;
            NJv[n * CH + c] = accJ[nn];
        }
    }
}

// ---------------- fused aggregate + post matmul + lin + BN stats -----------
// grid = NN/NPB = 3125 blocks of 256 threads (exact, no tail)
// Phase 1: wave w owns nodes {w, w+4}; lane gathers float4 (4 channels);
// x4 unroll = 4 independent 16B gathers in flight (x8 regressed: allocator
// stays at 64 VGPR and serializes — r9: VALUBusy 31->18%, 155->274us).
// apply_bn: X is pre-BN Hpre from previous layer (row-disjoint R/W safe).
__global__ __attribute__((amdgpu_waves_per_eu(4, 4))) __launch_bounds__(256)
void k_agg(
        const float* __restrict__ X, const float* __restrict__ A,
        const float* __restrict__ NJv, const int* __restrict__ offs,
        const int* __restrict__ adj, const float* __restrict__ avg_log_p,
        const float* __restrict__ post_w, const float* __restrict__ post_b,
        const float* __restrict__ lin_w, const float* __restrict__ lin_b,
        float* __restrict__ Hpre, float* __restrict__ bn_sum,
        float* __restrict__ bn_sum2,
        int apply_bn, const float* __restrict__ pbs, const float* __restrict__ pbs2,
        const float* __restrict__ pg, const float* __restrict__ pb2) {
    __shared__ __align__(16) float S[4][CH][SP];    // mean,min,max,std  [stat][ch][node(+pad)]
    __shared__ __align__(16) float xl[64][NPB];     // [f][node]; reused as Zl in phase 3
    __shared__ float ampl[NPB], ivampl[NPB];
    float (*Zl)[NPB] = xl;                          // alias: xl dead after region 0
    const int tid = threadIdx.x;
    const int base = blockIdx.x * NPB;
    const float avg_log = *avg_log_p;

#pragma unroll
    for (int r = 0; r < 2; ++r) {
        int idx = r * 256 + tid;
        int nn = idx >> 6, f = idx & 63;
        float xv = X[(base + nn) * 64 + f];
        if (apply_bn) xv = bn_relu(xv, f, pbs, pbs2, pg, pb2);
        xl[f][nn] = xv;
    }

    // ---- phase 1: per-node segment stats, float4-per-lane gather ----
    const int wid = tid >> 6, lane = tid & 63;
    const int c4 = lane << 2;                         // channel base (0,4,..252)
    const float4* __restrict__ njv4 = (const float4*)NJv;   // [n*64 + lane]
#pragma unroll
    for (int pass = 0; pass < 2; ++pass) {
        const int nn = wid + pass * 4;
        const int n = base + nn;
        const float4 a4 = *(const float4*)&A[n * CH + c4];
        const int e0 = offs[n], e1 = offs[n + 1];
        float4 s0, s1, q0, q1, mn, mx;
        s0.x=s0.y=s0.z=s0.w=0.f; s1=s0; q0=s0; q1=s0;
        mn.x=mn.y=mn.z=mn.w= __builtin_inff();
        mx.x=mx.y=mx.z=mx.w=-__builtin_inff();
        int e = e0;
        for (; e + 4 <= e1; e += 4) {
            int i0 = adj[e + 0];
            int i1 = adj[e + 1];
            int i2 = adj[e + 2];
            int i3 = adj[e + 3];
            float4 v0 = njv4[(size_t)i0 * 64 + lane];
            float4 v1 = njv4[(size_t)i1 * 64 + lane];
            float4 v2 = njv4[(size_t)i2 * 64 + lane];
            float4 v3 = njv4[(size_t)i3 * 64 + lane];
            ACC4(s0, q0, mn, mx, v0);
            ACC4(s1, q1, mn, mx, v1);
            ACC4(s0, q0, mn, mx, v2);
            ACC4(s1, q1, mn, mx, v3);
        }
        for (; e < e1; ++e) {
            int s = adj[e];
            float4 v = njv4[(size_t)s * 64 + lane];
            ACC4(s0, q0, mn, mx, v);
        }
        const float kf = (float)(e1 - e0);
        const float deg = fmaxf(kf, 1.f);
        const float inv_deg = 1.f / deg;
        const bool he = (e1 > e0);
        float bsum[4]  = { s0.x + s1.x, s0.y + s1.y, s0.z + s1.z, s0.w + s1.w };
        float bsum2[4] = { q0.x + q1.x, q0.y + q1.y, q0.z + q1.z, q0.w + q1.w };
        float bmin[4]  = { mn.x, mn.y, mn.z, mn.w };
        float bmax[4]  = { mx.x, mx.y, mx.z, mx.w };
        float av[4]    = { a4.x, a4.y, a4.z, a4.w };
#pragma unroll
        for (int j = 0; j < 4; ++j) {
            float a = av[j];
            float mean = (kf * a + bsum[j]) * inv_deg;
            float s2 = fmaf(kf * a, a, fmaf(2.f * a, bsum[j], bsum2[j]));
            float var = fmaxf(s2 * inv_deg - mean * mean, 0.f);
            float stdv = sqrtf(var + 1e-5f);
            int c = c4 + j;
            S[0][c][nn] = mean;
            S[1][c][nn] = he ? a + bmin[j] : 0.f;
            S[2][c][nn] = he ? a + bmax[j] : 0.f;
            S[3][c][nn] = stdv;
        }
        if (lane == 0) {
            float amp = logf(deg + 1.f) / avg_log;
            ampl[nn] = amp;
            ivampl[nn] = 1.f / amp;
        }
    }
    __syncthreads();

    // ---- phase 2: post matmul. group (o, q): o=output (t*16+go), q strides k
    const int o = tid >> 2, q = tid & 3;
    const int t = o >> 4;
    const float* pwrow = post_w + o * 832;
    float ax[8], aa[8], ab[8];
#pragma unroll
    for (int j = 0; j < 8; ++j) { ax[j] = 0.f; aa[j] = 0.f; ab[j] = 0.f; }
    // region 0: x broadcast, k in [0,64)  (xl aligned, b128 ok)
    for (int i = 0; i < 16; ++i) {
        int k = q + 4 * i;
        float w = pwrow[k];
        FMA8(ax, w, &xl[k][0]);
    }
    // regions 1-3 merged: read each S value once, 3 FMAs (w_amp, w_inv, w_id)
    for (int i = 0; i < 64; ++i) {
        int rem = q + 4 * i;
        const float* sr = &S[rem >> 6][(t << 6) | (rem & 63)][0];
        float w1 = pwrow[64 + rem];
        float w2 = pwrow[320 + rem];
        float w3 = pwrow[576 + rem];
        float sv[8];
#pragma unroll
        for (int j = 0; j < 8; ++j) sv[j] = sr[j];
#pragma unroll
        for (int j = 0; j < 8; ++j) {
            aa[j] = fmaf(w1, sv[j], aa[j]);
            ab[j] = fmaf(w2, sv[j], ab[j]);
            ax[j] = fmaf(w3, sv[j], ax[j]);
        }
    }
    float pb = post_b[o];
    float tot[8];
#pragma unroll
    for (int j = 0; j < 8; ++j) {
        float v = ax[j] + ampl[j] * aa[j] + ivampl[j] * ab[j];
        v += __shfl_xor(v, 1);
        v += __shfl_xor(v, 2);
        tot[j] = v + pb;
    }
    __syncthreads();            // all xl reads done; safe to overwrite (Zl alias)
    if (q == 0) {
#pragma unroll
        for (int j = 0; j < 8; ++j) Zl[o][j] = tot[j];
    }
    __syncthreads();

    // ---- phase 3: lin (64x64) + bias + BN stats ----
    const float* lrow = lin_w + o * 64;
    float la[8];
#pragma unroll
    for (int j = 0; j < 8; ++j) la[j] = 0.f;
    for (int i = 0; i < 16; ++i) {
        int c2 = q + 4 * i;
        float w = lrow[c2];
        FMA8(la, w, &Zl[c2][0]);
    }
#pragma unroll
    for (int j = 0; j < 8; ++j) {
        la[j] += __shfl_xor(la[j], 1);
        la[j] += __shfl_xor(la[j], 2);
    }
    if (q == 0) {
        float lb = lin_b[o];
        float s1 = 0.f, s2s = 0.f;
#pragma unroll
        for (int j = 0; j < 8; ++j) {
            float hv = la[j] + lb;
            Hpre[(base + j) * 64 + o] = hv;
            s1 += hv;
            s2s = fmaf(hv, hv, s2s);
        }
        atomicAdd(&bn_sum[o], s1);
        atomicAdd(&bn_sum2[o], s2s);
    }
}

// ---------------- fused 2-layer MLP (applies bn2 inline) -------------------
__global__ __launch_bounds__(256) void k_mlp(
        const float* __restrict__ Hpre, const float* __restrict__ w1,
        const float* __restrict__ b1, const float* __restrict__ w2,
        const float* __restrict__ b2, float* __restrict__ out,
        const float* __restrict__ bs, const float* __restrict__ bs2,
        const float* __restrict__ bng, const float* __restrict__ bnb) {
    __shared__ __align__(16) float xl[64][NPB];
    __shared__ __align__(16) float hl[64][NPB];
    const int tid = threadIdx.x;
    const int base = blockIdx.x * NPB;
#pragma unroll
    for (int r = 0; r < 2; ++r) {
        int idx = r * 256 + tid;
        int nn = idx >> 6, f = idx & 63;
        xl[f][nn] = bn_relu(Hpre[(base + nn) * 64 + f], f, bs, bs2, bng, bnb);
    }
    __syncthreads();
    const int o = tid >> 2, q = tid & 3;
    const float* wrow = w1 + o * 64;
    float acc[8];
#pragma unroll
    for (int j = 0; j < 8; ++j) acc[j] = 0.f;
    for (int i = 0; i < 16; ++i) {
        int c2 = q + 4 * i;
        float w = wrow[c2];
        FMA8(acc, w, &xl[c2][0]);
    }
#pragma unroll
    for (int j = 0; j < 8; ++j) {
        acc[j] += __shfl_xor(acc[j], 1);
        acc[j] += __shfl_xor(acc[j], 2);
    }
    if (q == 0) {
        float bb = b1[o];
#pragma unroll
        for (int j = 0; j < 8; ++j) hl[o][j] = fmaxf(acc[j] + bb, 0.f);
    }
    __syncthreads();
    // layer 2: 32 outputs, groups of 8 threads
    const int o2 = tid >> 3, q2 = tid & 7;
    const float* w2row = w2 + o2 * 64;
    float a2[8];
#pragma unroll
    for (int j = 0; j < 8; ++j) a2[j] = 0.f;
    for (int i = 0; i < 8; ++i) {
        int c2 = q2 + 8 * i;
        float w = w2row[c2];
        FMA8(a2, w, &hl[c2][0]);
    }
#pragma unroll
    for (int j = 0; j < 8; ++j) {
        a2[j] += __shfl_xor(a2[j], 1);
        a2[j] += __shfl_xor(a2[j], 2);
        a2[j] += __shfl_xor(a2[j], 4);
    }
    if (q2 == 0) {
        float bb = b2[o2];
#pragma unroll
        for (int j = 0; j < 8; ++j) out[(base + j) * 32 + o2] = a2[j] + bb;
    }
}

// ---------------------------------------------------------------------------
extern "C" void kernel_launch(void* const* d_in, const int* in_sizes, int n_in,
                              void* d_out, int out_size, void* d_ws, size_t ws_size,
                              hipStream_t stream) {
    (void)in_sizes; (void)n_in; (void)out_size; (void)ws_size;
    const float* x         = (const float*)d_in[0];
    const int*   ei        = (const int*)d_in[1];
    const float* c1_pre_w  = (const float*)d_in[2];
    const float* c1_pre_b  = (const float*)d_in[3];
    const float* c1_post_w = (const float*)d_in[4];
    const float* c1_post_b = (const float*)d_in[5];
    const float* c1_lin_w  = (const float*)d_in[6];
    const float* c1_lin_b  = (const float*)d_in[7];
    const float* c2_pre_w  = (const float*)d_in[8];
    const float* c2_pre_b  = (const float*)d_in[9];
    const float* c2_post_w = (const float*)d_in[10];
    const float* c2_post_b = (const float*)d_in[11];
    const float* c2_lin_w  = (const float*)d_in[12];
    const float* c2_lin_b  = (const float*)d_in[13];
    const float* bn1_g     = (const float*)d_in[14];
    const float* bn1_b     = (const float*)d_in[15];
    const float* bn2_g     = (const float*)d_in[16];
    const float* bn2_b     = (const float*)d_in[17];
    const float* mlp_w1    = (const float*)d_in[18];
    const float* mlp_b1    = (const float*)d_in[19];
    const float* mlp_w2    = (const float*)d_in[20];
    const float* mlp_b2    = (const float*)d_in[21];

    const int* src = ei;          // edge_index[0]
    const int* dst = ei + NE;     // edge_index[1]

    // workspace layout (all 4-byte elements)
    int*   cnt    = (int*)d_ws;                 // N        (zeroed)
    int*   cursor = cnt + NN;                   // N        (zeroed)
    float* bn1s   = (float*)(cursor + NN);      // 64       (zeroed)
    float* bn1s2  = bn1s + 64;                  // 64       (zeroed)
    float* bn2s   = bn1s2 + 64;                 // 64       (zeroed)
    float* bn2s2  = bn2s + 64;                  // 64       (zeroed)
    int*   offs   = (int*)(bn2s2 + 64);         // N+1
    float* avgl   = (float*)(offs + NN + 1);    // 1
    int*   adj    = (int*)(avgl + 1);           // E
    float* wit    = (float*)(adj + NE);         // 64*256
    float* wjt    = wit + 64 * CH;              // 64*256
    float* A      = wjt + 64 * CH;              // N*256
    float* NJv    = A + (size_t)NN * CH;        // N*256
    float* Hpre   = NJv + (size_t)NN * CH;      // N*64

    hipMemsetAsync(d_ws, 0, (size_t)(2 * NN + 256) * sizeof(int), stream);

    k_hist   <<<(NE + 255) / 256, 256, 0, stream>>>(dst, cnt);
    k_scan   <<<1, 1024, 0, stream>>>(cnt, offs, avgl);
    k_scatter<<<(NE + 255) / 256, 256, 0, stream>>>(src, dst, offs, cursor, adj);

    // layer 1
    k_wt <<<64, 256, 0, stream>>>(c1_pre_w, wit, wjt);
    k_pre<<<(NN + 15) / 16, 256, 0, stream>>>(x, wit, wjt, c1_pre_b, A, NJv,
                                              0, nullptr, nullptr, nullptr, nullptr);
    k_agg<<<NN / NPB, 256, 0, stream>>>(x, A, NJv, offs, adj, avgl,
                                        c1_post_w, c1_post_b, c1_lin_w, c1_lin_b,
                                        Hpre, bn1s, bn1s2,
                                        0, nullptr, nullptr, nullptr, nullptr);

    // layer 2 (bn1 applied inline by consumers of Hpre)
    k_wt <<<64, 256, 0, stream>>>(c2_pre_w, wit, wjt);
    k_pre<<<(NN + 15) / 16, 256, 0, stream>>>(Hpre, wit, wjt, c2_pre_b, A, NJv,
                                              1, bn1s, bn1s2, bn1_g, bn1_b);
    k_agg<<<NN / NPB, 256, 0, stream>>>(Hpre, A, NJv, offs, adj, avgl,
                                        c2_post_w, c2_post_b, c2_lin_w, c2_lin_b,
                                        Hpre, bn2s, bn2s2,
                                        1, bn1s, bn1s2, bn1_g, bn1_b);

    // MLP head (bn2 applied inline)
    k_mlp<<<NN / NPB, 256, 0, stream>>>(Hpre, mlp_w1, mlp_b1, mlp_w2, mlp_b2,
                                        (float*)d_out, bn2s, bn2s2, bn2_g, bn2_b);
}

// Round 12
// 587.978 us; speedup vs baseline: 1.2049x; 1.1983x over previous
//
#include <hip/hip_runtime.h>
#include <math.h>

#define NN 25000
#define NE 400000
#define CH 256          // T*64 channels
#define NPB 8           // nodes per block in agg/mlp
#define SP 9            // padded node-dim of S (breaks single-bank column)

// ---------------- FMA helper: acc[0..7] += w * ptr[0..7] (LDS, b128 pairs) --
#define FMA8(dst, w, ptr) do {                                   \
    const float4 _u0 = *(const float4*)(ptr);                    \
    const float4 _u1 = *(const float4*)((ptr)+4);                \
    dst[0]=fmaf((w),_u0.x,dst[0]); dst[1]=fmaf((w),_u0.y,dst[1]);\
    dst[2]=fmaf((w),_u0.z,dst[2]); dst[3]=fmaf((w),_u0.w,dst[3]);\
    dst[4]=fmaf((w),_u1.x,dst[4]); dst[5]=fmaf((w),_u1.y,dst[5]);\
    dst[6]=fmaf((w),_u1.z,dst[6]); dst[7]=fmaf((w),_u1.w,dst[7]);} while(0)

// component-wise accumulate of one gathered float4
#define ACC4(sv, qv, mnv, mxv, v) do {                                  \
    sv.x += v.x; qv.x = fmaf(v.x, v.x, qv.x);                           \
    mnv.x = fminf(mnv.x, v.x); mxv.x = fmaxf(mxv.x, v.x);               \
    sv.y += v.y; qv.y = fmaf(v.y, v.y, qv.y);                           \
    mnv.y = fminf(mnv.y, v.y); mxv.y = fmaxf(mxv.y, v.y);               \
    sv.z += v.z; qv.z = fmaf(v.z, v.z, qv.z);                           \
    mnv.z = fminf(mnv.z, v.z); mxv.z = fmaxf(mxv.z, v.z);               \
    sv.w += v.w; qv.w = fmaf(v.w, v.w, qv.w);                           \
    mnv.w = fminf(mnv.w, v.w); mxv.w = fmaxf(mxv.w, v.w); } while(0)

// BN-apply + ReLU on a loaded value (stats via bn_sum/bn_sum2 atomics)
__device__ __forceinline__ float bn_relu(float x, int c, const float* bs,
                                         const float* bs2, const float* g,
                                         const float* b) {
    const float invN = 1.f / (float)NN;
    float m = bs[c] * invN;
    float v = bs2[c] * invN - m * m;
    float sc = g[c] / sqrtf(v + 1e-5f);
    return fmaxf(sc * (x - m) + b[c], 0.f);
}

// ---------------- degree histogram -----------------------------------------
__global__ void k_hist(const int* __restrict__ dst, int* __restrict__ cnt) {
    int e = blockIdx.x * 256 + threadIdx.x;
    if (e < NE) atomicAdd(&cnt[dst[e]], 1);
}

// ---------------- single-block scan (1024 thr, 2-pass, ~3 barriers) --------
__global__ __launch_bounds__(1024) void k_scan(const int* __restrict__ cnt,
                                               int* __restrict__ offs,
                                               float* __restrict__ avg_log) {
    __shared__ int wsum[16];
    __shared__ float wlog[16];
    const int tid = threadIdx.x;
    const int lane = tid & 63, wv = tid >> 6;
    const int PER = (NN + 1023) / 1024;   // 25 contiguous elements per thread
    const int start = tid * PER;
    int lsum = 0;
    float llog = 0.f;
    for (int j = 0; j < PER; ++j) {
        int i = start + j;
        if (i < NN) {
            int c = cnt[i];
            lsum += c;
            llog += logf((float)c + 1.f);
        }
    }
    // wave-inclusive scan of per-thread sums
    int v = lsum;
    for (int d = 1; d < 64; d <<= 1) {
        int t = __shfl_up(v, d);
        if (lane >= d) v += t;
    }
    if (lane == 63) wsum[wv] = v;
    float lg = llog;
    for (int d = 32; d > 0; d >>= 1) lg += __shfl_xor(lg, d);
    if (lane == 0) wlog[wv] = lg;
    __syncthreads();
    if (tid == 0) {
        int run = 0;
        for (int w = 0; w < 16; ++w) { int t = wsum[w]; wsum[w] = run; run += t; }
        offs[NN] = run;
        float lt = 0.f;
        for (int w = 0; w < 16; ++w) lt += wlog[w];
        *avg_log = lt / (float)NN;
    }
    __syncthreads();
    int base = wsum[wv] + (v - lsum);   // exclusive prefix for this thread
    for (int j = 0; j < PER; ++j) {
        int i = start + j;
        if (i < NN) {
            offs[i] = base;
            base += cnt[i];
        }
    }
}

// ---------------- CSR scatter ----------------------------------------------
__global__ void k_scatter(const int* __restrict__ src, const int* __restrict__ dst,
                          const int* __restrict__ offs, int* __restrict__ cursor,
                          int* __restrict__ adj) {
    int e = blockIdx.x * 256 + threadIdx.x;
    if (e < NE) {
        int d = dst[e];
        int p = atomicAdd(&cursor[d], 1);
        adj[offs[d] + p] = src[e];
    }
}

// ---------------- transpose pre weights: wit/wjt [f][c], c=t*64+g ----------
__global__ void k_wt(const float* __restrict__ pre_w, float* __restrict__ wit,
                     float* __restrict__ wjt) {
    int i = blockIdx.x * 256 + threadIdx.x;   // over 64*256
    int f = i >> 8, c = i & 255;
    int t = c >> 6, g = c & 63;
    wit[f * CH + c] = pre_w[(t * 64 + g) * 128 + f];
    wjt[f * CH + c] = pre_w[(t * 64 + g) * 128 + 64 + f];
}

// ---------------- pre GEMM: A = X@Wi^T + pre_b, NJ = X@Wj^T ----------------
// apply_bn: input X is pre-BN (Hpre); apply bn_relu inline while staging and
// ALSO write the activated value to Hout (so k_agg/k_mlp read it plain —
// keeping bn code OUT of k_agg, whose gather schedule it wrecks: r9/r11
// 155->276us even with apply_bn=0; codegen is body-size sensitive).
__global__ __launch_bounds__(256) void k_pre(
        const float* __restrict__ X, const float* __restrict__ wit,
        const float* __restrict__ wjt, const float* __restrict__ pre_b,
        float* __restrict__ A, float* __restrict__ NJv,
        int apply_bn, const float* __restrict__ bs, const float* __restrict__ bs2,
        const float* __restrict__ bng, const float* __restrict__ bnb,
        float* __restrict__ Hout) {
    __shared__ __align__(16) float xl[16][64];
    const int tid = threadIdx.x;
    const int base = blockIdx.x * 16;
#pragma unroll
    for (int r = 0; r < 4; ++r) {
        int idx = r * 256 + tid;
        int nn = idx >> 6, f = idx & 63;
        int n = base + nn;
        float xv = (n < NN) ? X[n * 64 + f] : 0.f;
        if (apply_bn) {
            xv = bn_relu(xv, f, bs, bs2, bng, bnb);
            if (n < NN) Hout[n * 64 + f] = xv;
        }
        xl[nn][f] = xv;
    }
    __syncthreads();
    const int c = tid;
    float accA[16], accJ[16];
#pragma unroll
    for (int j = 0; j < 16; ++j) { accA[j] = 0.f; accJ[j] = 0.f; }
#pragma unroll 4
    for (int f = 0; f < 64; ++f) {
        float wa = wit[f * CH + c];
        float wb = wjt[f * CH + c];
#pragma unroll
        for (int nn = 0; nn < 16; ++nn) {
            float xv = xl[nn][f];
            accA[nn] = fmaf(wa, xv, accA[nn]);
            accJ[nn] = fmaf(wb, xv, accJ[nn]);
        }
    }
    float pb = pre_b[c];
#pragma unroll
    for (int nn = 0; nn < 16; ++nn) {
        int n = base + nn;
        if (n < NN) {
            A[n * CH + c]   = accA[nn] + pb;
            NJv[n * CH + c] = accJ[nn];
        }
    }
}

// ---------------- fused aggregate + post matmul + lin + BN stats -----------
// EXACT r8-measured form (155us/dispatch): no BN code in this kernel.
// grid = NN/NPB = 3125 blocks of 256 threads (exact, no tail)
// Phase 1: wave w owns nodes {w, w+4}; lane gathers float4 (4 channels);
// x4 unroll = 4 independent 16B gathers in flight.
// waves_per_eu(4,4): forbid the 8-wave/64-VGPR spill heuristic (r6: 220MB
// scratch writes). S padded to [4][256][9]: write bank (4l+9j+nn)%32 = 8-way.
__global__ __attribute__((amdgpu_waves_per_eu(4, 4))) __launch_bounds__(256)
void k_agg(
        const float* __restrict__ X, const float* __restrict__ A,
        const float* __restrict__ NJv, const int* __restrict__ offs,
        const int* __restrict__ adj, const float* __restrict__ avg_log_p,
        const float* __restrict__ post_w, const float* __restrict__ post_b,
        const float* __restrict__ lin_w, const float* __restrict__ lin_b,
        float* __restrict__ Hpre, float* __restrict__ bn_sum,
        float* __restrict__ bn_sum2) {
    __shared__ __align__(16) float S[4][CH][SP];    // mean,min,max,std  [stat][ch][node(+pad)]
    __shared__ __align__(16) float xl[64][NPB];     // [f][node]; reused as Zl in phase 3
    __shared__ float ampl[NPB], ivampl[NPB];
    float (*Zl)[NPB] = xl;                          // alias: xl dead after region 0
    const int tid = threadIdx.x;
    const int base = blockIdx.x * NPB;
    const float avg_log = *avg_log_p;

#pragma unroll
    for (int r = 0; r < 2; ++r) {
        int idx = r * 256 + tid;
        int nn = idx >> 6, f = idx & 63;
        xl[f][nn] = X[(base + nn) * 64 + f];
    }

    // ---- phase 1: per-node segment stats, float4-per-lane gather ----
    const int wid = tid >> 6, lane = tid & 63;
    const int c4 = lane << 2;                         // channel base (0,4,..252)
    const float4* __restrict__ njv4 = (const float4*)NJv;   // [n*64 + lane]
#pragma unroll
    for (int pass = 0; pass < 2; ++pass) {
        const int nn = wid + pass * 4;
        const int n = base + nn;
        const float4 a4 = *(const float4*)&A[n * CH + c4];
        const int e0 = offs[n], e1 = offs[n + 1];
        float4 s0, s1, q0, q1, mn, mx;
        s0.x=s0.y=s0.z=s0.w=0.f; s1=s0; q0=s0; q1=s0;
        mn.x=mn.y=mn.z=mn.w= __builtin_inff();
        mx.x=mx.y=mx.z=mx.w=-__builtin_inff();
        int e = e0;
        for (; e + 4 <= e1; e += 4) {
            int i0 = adj[e + 0];
            int i1 = adj[e + 1];
            int i2 = adj[e + 2];
            int i3 = adj[e + 3];
            float4 v0 = njv4[(size_t)i0 * 64 + lane];
            float4 v1 = njv4[(size_t)i1 * 64 + lane];
            float4 v2 = njv4[(size_t)i2 * 64 + lane];
            float4 v3 = njv4[(size_t)i3 * 64 + lane];
            ACC4(s0, q0, mn, mx, v0);
            ACC4(s1, q1, mn, mx, v1);
            ACC4(s0, q0, mn, mx, v2);
            ACC4(s1, q1, mn, mx, v3);
        }
        for (; e < e1; ++e) {
            int s = adj[e];
            float4 v = njv4[(size_t)s * 64 + lane];
            ACC4(s0, q0, mn, mx, v);
        }
        const float kf = (float)(e1 - e0);
        const float deg = fmaxf(kf, 1.f);
        const float inv_deg = 1.f / deg;
        const bool he = (e1 > e0);
        float bsum[4]  = { s0.x + s1.x, s0.y + s1.y, s0.z + s1.z, s0.w + s1.w };
        float bsum2[4] = { q0.x + q1.x, q0.y + q1.y, q0.z + q1.z, q0.w + q1.w };
        float bmin[4]  = { mn.x, mn.y, mn.z, mn.w };
        float bmax[4]  = { mx.x, mx.y, mx.z, mx.w };
        float av[4]    = { a4.x, a4.y, a4.z, a4.w };
#pragma unroll
        for (int j = 0; j < 4; ++j) {
            float a = av[j];
            float mean = (kf * a + bsum[j]) * inv_deg;
            float s2 = fmaf(kf * a, a, fmaf(2.f * a, bsum[j], bsum2[j]));
            float var = fmaxf(s2 * inv_deg - mean * mean, 0.f);
            float stdv = sqrtf(var + 1e-5f);
            int c = c4 + j;
            S[0][c][nn] = mean;
            S[1][c][nn] = he ? a + bmin[j] : 0.f;
            S[2][c][nn] = he ? a + bmax[j] : 0.f;
            S[3][c][nn] = stdv;
        }
        if (lane == 0) {
            float amp = logf(deg + 1.f) / avg_log;
            ampl[nn] = amp;
            ivampl[nn] = 1.f / amp;
        }
    }
    __syncthreads();

    // ---- phase 2: post matmul. group (o, q): o=output (t*16+go), q strides k
    const int o = tid >> 2, q = tid & 3;
    const int t = o >> 4;
    const float* pwrow = post_w + o * 832;
    float ax[8], aa[8], ab[8];
#pragma unroll
    for (int j = 0; j < 8; ++j) { ax[j] = 0.f; aa[j] = 0.f; ab[j] = 0.f; }
    // region 0: x broadcast, k in [0,64)  (xl aligned, b128 ok)
    for (int i = 0; i < 16; ++i) {
        int k = q + 4 * i;
        float w = pwrow[k];
        FMA8(ax, w, &xl[k][0]);
    }
    // regions 1-3 merged: read each S value once, 3 FMAs (w_amp, w_inv, w_id)
    for (int i = 0; i < 64; ++i) {
        int rem = q + 4 * i;
        const float* sr = &S[rem >> 6][(t << 6) | (rem & 63)][0];
        float w1 = pwrow[64 + rem];
        float w2 = pwrow[320 + rem];
        float w3 = pwrow[576 + rem];
        float sv[8];
#pragma unroll
        for (int j = 0; j < 8; ++j) sv[j] = sr[j];
#pragma unroll
        for (int j = 0; j < 8; ++j) {
            aa[j] = fmaf(w1, sv[j], aa[j]);
            ab[j] = fmaf(w2, sv[j], ab[j]);
            ax[j] = fmaf(w3, sv[j], ax[j]);
        }
    }
    float pb = post_b[o];
    float tot[8];
#pragma unroll
    for (int j = 0; j < 8; ++j) {
        float v = ax[j] + ampl[j] * aa[j] + ivampl[j] * ab[j];
        v += __shfl_xor(v, 1);
        v += __shfl_xor(v, 2);
        tot[j] = v + pb;
    }
    __syncthreads();            // all xl reads done; safe to overwrite (Zl alias)
    if (q == 0) {
#pragma unroll
        for (int j = 0; j < 8; ++j) Zl[o][j] = tot[j];
    }
    __syncthreads();

    // ---- phase 3: lin (64x64) + bias + BN stats ----
    const float* lrow = lin_w + o * 64;
    float la[8];
#pragma unroll
    for (int j = 0; j < 8; ++j) la[j] = 0.f;
    for (int i = 0; i < 16; ++i) {
        int c2 = q + 4 * i;
        float w = lrow[c2];
        FMA8(la, w, &Zl[c2][0]);
    }
#pragma unroll
    for (int j = 0; j < 8; ++j) {
        la[j] += __shfl_xor(la[j], 1);
        la[j] += __shfl_xor(la[j], 2);
    }
    if (q == 0) {
        float lb = lin_b[o];
        float s1 = 0.f, s2s = 0.f;
#pragma unroll
        for (int j = 0; j < 8; ++j) {
            float hv = la[j] + lb;
            Hpre[(base + j) * 64 + o] = hv;
            s1 += hv;
            s2s = fmaf(hv, hv, s2s);
        }
        atomicAdd(&bn_sum[o], s1);
        atomicAdd(&bn_sum2[o], s2s);
    }
}

// ---------------- fused 2-layer MLP (applies bn2 inline) -------------------
__global__ __launch_bounds__(256) void k_mlp(
        const float* __restrict__ Hpre, const float* __restrict__ w1,
        const float* __restrict__ b1, const float* __restrict__ w2,
        const float* __restrict__ b2, float* __restrict__ out,
        const float* __restrict__ bs, const float* __restrict__ bs2,
        const float* __restrict__ bng, const float* __restrict__ bnb) {
    __shared__ __align__(16) float xl[64][NPB];
    __shared__ __align__(16) float hl[64][NPB];
    const int tid = threadIdx.x;
    const int base = blockIdx.x * NPB;
#pragma unroll
    for (int r = 0; r < 2; ++r) {
        int idx = r * 256 + tid;
        int nn = idx >> 6, f = idx & 63;
        xl[f][nn] = bn_relu(Hpre[(base + nn) * 64 + f], f, bs, bs2, bng, bnb);
    }
    __syncthreads();
    const int o = tid >> 2, q = tid & 3;
    const float* wrow = w1 + o * 64;
    float acc[8];
#pragma unroll
    for (int j = 0; j < 8; ++j) acc[j] = 0.f;
    for (int i = 0; i < 16; ++i) {
        int c2 = q + 4 * i;
        float w = wrow[c2];
        FMA8(acc, w, &xl[c2][0]);
    }
#pragma unroll
    for (int j = 0; j < 8; ++j) {
        acc[j] += __shfl_xor(acc[j], 1);
        acc[j] += __shfl_xor(acc[j], 2);
    }
    if (q == 0) {
        float bb = b1[o];
#pragma unroll
        for (int j = 0; j < 8; ++j) hl[o][j] = fmaxf(acc[j] + bb, 0.f);
    }
    __syncthreads();
    // layer 2: 32 outputs, groups of 8 threads
    const int o2 = tid >> 3, q2 = tid & 7;
    const float* w2row = w2 + o2 * 64;
    float a2[8];
#pragma unroll
    for (int j = 0; j < 8; ++j) a2[j] = 0.f;
    for (int i = 0; i < 8; ++i) {
        int c2 = q2 + 8 * i;
        float w = w2row[c2];
        FMA8(a2, w, &hl[c2][0]);
    }
#pragma unroll
    for (int j = 0; j < 8; ++j) {
        a2[j] += __shfl_xor(a2[j], 1);
        a2[j] += __shfl_xor(a2[j], 2);
        a2[j] += __shfl_xor(a2[j], 4);
    }
    if (q2 == 0) {
        float bb = b2[o2];
#pragma unroll
        for (int j = 0; j < 8; ++j) out[(base + j) * 32 + o2] = a2[j] + bb;
    }
}

// ---------------------------------------------------------------------------
extern "C" void kernel_launch(void* const* d_in, const int* in_sizes, int n_in,
                              void* d_out, int out_size, void* d_ws, size_t ws_size,
                              hipStream_t stream) {
    (void)in_sizes; (void)n_in; (void)out_size; (void)ws_size;
    const float* x         = (const float*)d_in[0];
    const int*   ei        = (const int*)d_in[1];
    const float* c1_pre_w  = (const float*)d_in[2];
    const float* c1_pre_b  = (const float*)d_in[3];
    const float* c1_post_w = (const float*)d_in[4];
    const float* c1_post_b = (const float*)d_in[5];
    const float* c1_lin_w  = (const float*)d_in[6];
    const float* c1_lin_b  = (const float*)d_in[7];
    const float* c2_pre_w  = (const float*)d_in[8];
    const float* c2_pre_b  = (const float*)d_in[9];
    const float* c2_post_w = (const float*)d_in[10];
    const float* c2_post_b = (const float*)d_in[11];
    const float* c2_lin_w  = (const float*)d_in[12];
    const float* c2_lin_b  = (const float*)d_in[13];
    const float* bn1_g     = (const float*)d_in[14];
    const float* bn1_b     = (const float*)d_in[15];
    const float* bn2_g     = (const float*)d_in[16];
    const float* bn2_b     = (const float*)d_in[17];
    const float* mlp_w1    = (const float*)d_in[18];
    const float* mlp_b1    = (const float*)d_in[19];
    const float* mlp_w2    = (const float*)d_in[20];
    const float* mlp_b2    = (const float*)d_in[21];

    const int* src = ei;          // edge_index[0]
    const int* dst = ei + NE;     // edge_index[1]

    // workspace layout (all 4-byte elements)
    int*   cnt    = (int*)d_ws;                 // N        (zeroed)
    int*   cursor = cnt + NN;                   // N        (zeroed)
    float* bn1s   = (float*)(cursor + NN);      // 64       (zeroed)
    float* bn1s2  = bn1s + 64;                  // 64       (zeroed)
    float* bn2s   = bn1s2 + 64;                 // 64       (zeroed)
    float* bn2s2  = bn2s + 64;                  // 64       (zeroed)
    int*   offs   = (int*)(bn2s2 + 64);         // N+1
    float* avgl   = (float*)(offs + NN + 1);    // 1
    int*   adj    = (int*)(avgl + 1);           // E
    float* wit    = (float*)(adj + NE);         // 64*256
    float* wjt    = wit + 64 * CH;              // 64*256
    float* A      = wjt + 64 * CH;              // N*256
    float* NJv    = A + (size_t)NN * CH;        // N*256
    float* Hpre   = NJv + (size_t)NN * CH;      // N*64
    float* H      = Hpre + (size_t)NN * 64;     // N*64 (bn1-activated)

    hipMemsetAsync(d_ws, 0, (size_t)(2 * NN + 256) * sizeof(int), stream);

    k_hist   <<<(NE + 255) / 256, 256, 0, stream>>>(dst, cnt);
    k_scan   <<<1, 1024, 0, stream>>>(cnt, offs, avgl);
    k_scatter<<<(NE + 255) / 256, 256, 0, stream>>>(src, dst, offs, cursor, adj);

    // layer 1
    k_wt <<<64, 256, 0, stream>>>(c1_pre_w, wit, wjt);
    k_pre<<<(NN + 15) / 16, 256, 0, stream>>>(x, wit, wjt, c1_pre_b, A, NJv,
                                              0, nullptr, nullptr, nullptr, nullptr,
                                              nullptr);
    k_agg<<<NN / NPB, 256, 0, stream>>>(x, A, NJv, offs, adj, avgl,
                                        c1_post_w, c1_post_b, c1_lin_w, c1_lin_b,
                                        Hpre, bn1s, bn1s2);

    // layer 2: k_pre applies bn1 inline and materializes H = bn_relu(Hpre)
    k_wt <<<64, 256, 0, stream>>>(c2_pre_w, wit, wjt);
    k_pre<<<(NN + 15) / 16, 256, 0, stream>>>(Hpre, wit, wjt, c2_pre_b, A, NJv,
                                              1, bn1s, bn1s2, bn1_g, bn1_b, H);
    k_agg<<<NN / NPB, 256, 0, stream>>>(H, A, NJv, offs, adj, avgl,
                                        c2_post_w, c2_post_b, c2_lin_w, c2_lin_b,
                                        Hpre, bn2s, bn2s2);

    // MLP head (bn2 applied inline)
    k_mlp<<<NN / NPB, 256, 0, stream>>>(Hpre, mlp_w1, mlp_b1, mlp_w2, mlp_b2,
                                        (float*)d_out, bn2s, bn2s2, bn2_g, bn2_b);
}